// Round 1
// baseline (194.405 us; speedup 1.0000x reference)
//
#include <hip/hip_runtime.h>
#include <cstdint>

// Problem constants (reference: DIM=1024, N=8192)
#define DIMD 1024
#define NROWS 8192
#define KDIM 2048   // 2*DIM

typedef unsigned short u16;
typedef __bf16 bf16x8 __attribute__((ext_vector_type(8)));
typedef float f32x4 __attribute__((ext_vector_type(4)));

__device__ __forceinline__ u16 f2bf(float f) {
  unsigned u = __builtin_bit_cast(unsigned, f);
  unsigned r = (u + 0x7FFFu + ((u >> 16) & 1u)) >> 16;  // RNE, finite inputs
  return (u16)r;
}

// ---------------------------------------------------------------------------
// Kernel 1: shared conv rows. shared[c][w] = conv_b[c] + sum_{h=0,1} sum_k
//           conv_w[c,0,h,k] * trow_h[w+k-2]  (zero pad). 2048 outputs.
// ---------------------------------------------------------------------------
__global__ void prep_shared(const float* __restrict__ tn, const float* __restrict__ ta,
                            const float* __restrict__ cw, const float* __restrict__ cb,
                            float* __restrict__ shws) {
  int t = blockIdx.x * blockDim.x + threadIdx.x;  // 0..2047
  if (t >= 2 * DIMD) return;
  int c = t >> 10, w = t & (DIMD - 1);
  float s = cb[c];
#pragma unroll
  for (int h = 0; h < 2; ++h) {
    const float* row = h ? ta : tn;
#pragma unroll
    for (int k = 0; k < 5; ++k) {
      int wp = w + k - 2;
      if (0 <= wp && wp < DIMD) s += cw[c * 15 + h * 5 + k] * row[wp];
    }
  }
  shws[t] = s;
}

// ---------------------------------------------------------------------------
// Kernel 2: w2 fp32 -> bf16. 2,097,152 elements, 8 per thread.
// ---------------------------------------------------------------------------
__global__ void cast_w2(const float* __restrict__ w2, u16* __restrict__ w2b) {
  int t = blockIdx.x * blockDim.x + threadIdx.x;  // 0..262143
  const float4* p = (const float4*)(w2 + (size_t)t * 8);
  float4 a = p[0], b = p[1];
  union { u16 o[8]; uint4 v; } pk;
  pk.o[0] = f2bf(a.x); pk.o[1] = f2bf(a.y); pk.o[2] = f2bf(a.z); pk.o[3] = f2bf(a.w);
  pk.o[4] = f2bf(b.x); pk.o[5] = f2bf(b.y); pk.o[6] = f2bf(b.z); pk.o[7] = f2bf(b.w);
  *(uint4*)(w2b + (size_t)t * 8) = pk.v;
}

// ---------------------------------------------------------------------------
// Kernel 3: x2[i][c*1024+w] = gelu_exact(shared[c][w] + sum_k cw[c,2,k]*if[i][w+k-2])
// 8 outputs / thread along w; bf16 16B store.
// ---------------------------------------------------------------------------
__global__ void conv_gelu(const float* __restrict__ ifeats, const float* __restrict__ shws,
                          const float* __restrict__ cw, u16* __restrict__ x2) {
  int t = blockIdx.x * blockDim.x + threadIdx.x;  // 0..2,097,151
  int i = t >> 8;                 // row (2048/8 = 256 groups per row)
  int rem = t & 255;
  int c = rem >> 7;               // channel 0/1
  int w0 = (rem & 127) << 3;      // 0..1016
  float wk[5];
#pragma unroll
  for (int k = 0; k < 5; ++k) wk[k] = cw[c * 15 + 10 + k];  // h=2 tap row
  float v[12];
  const float* row = ifeats + (size_t)i * DIMD;
#pragma unroll
  for (int j = 0; j < 12; ++j) {
    int wp = w0 - 2 + j;
    v[j] = (wp >= 0 && wp < DIMD) ? row[wp] : 0.f;
  }
  union { u16 o[8]; uint4 u; } pk;
#pragma unroll
  for (int s = 0; s < 8; ++s) {
    float x = shws[c * DIMD + w0 + s];
#pragma unroll
    for (int k = 0; k < 5; ++k) x += wk[k] * v[s + k];
    float g = 0.5f * x * (1.0f + erff(x * 0.70710678118654752f));  // exact gelu
    pk.o[s] = f2bf(g);
  }
  *(uint4*)(x2 + (size_t)i * KDIM + c * DIMD + w0) = pk.u;
}

// ---------------------------------------------------------------------------
// Kernel 4: out[i][j] = ifeats[i][j] + b2[j] + sum_k x2[i][k] * w2b[j][k]
// m97-style: 128x128 tile, BK=32, 4 waves, 4x4 MFMA 16x16x32 bf16 per wave,
// global_load_lds width=16 staging into unpadded [128][32] LDS tiles.
// ---------------------------------------------------------------------------
__device__ __forceinline__ void gl_lds16(const u16* g, u16* l) {
  __builtin_amdgcn_global_load_lds(
      (__attribute__((address_space(1))) void*)g,
      (__attribute__((address_space(3))) void*)l, 16, 0, 0);
}

__global__ __launch_bounds__(256) void gemm_bt(
    const u16* __restrict__ A,      // x2 bf16 [8192, 2048]
    const u16* __restrict__ B,      // w2 bf16 [1024, 2048]
    const float* __restrict__ ifeats,
    const float* __restrict__ b2,
    float* __restrict__ out) {
  constexpr int K = KDIM;
  __shared__ __align__(16) u16 sA[128 * 32];
  __shared__ __align__(16) u16 sB[128 * 32];

  const int tid = threadIdx.x;
  const int wv = tid >> 6;         // wave 0..3
  const int lane = tid & 63;
  const int i0 = blockIdx.y * 128; // M block
  const int j0 = blockIdx.x * 128; // N block
  const int wm = (wv & 1) * 64;    // wave quadrant
  const int wn = (wv >> 1) * 64;

  // staging: each wave stages 32 rows of A and 32 rows of B (2 issues each,
  // 16 rows/issue: lane -> row=lane/4, 16B chunk=(lane&3)*16B). LDS layout is
  // exactly base + lane*16 (global_load_lds is wave-uniform-base + lane*size).
  const int srow = lane >> 2;
  const int scol = (lane & 3) * 8;
  const u16* ga0 = A + (size_t)(i0 + wv * 32 + srow) * K + scol;
  const u16* ga1 = ga0 + (size_t)16 * K;
  const u16* gb0 = B + (size_t)(j0 + wv * 32 + srow) * K + scol;
  const u16* gb1 = gb0 + (size_t)16 * K;
  u16* la0 = sA + (wv * 32 + 0) * 32;
  u16* la1 = sA + (wv * 32 + 16) * 32;
  u16* lb0 = sB + (wv * 32 + 0) * 32;
  u16* lb1 = sB + (wv * 32 + 16) * 32;

  const int quad = lane >> 4;      // 0..3
  const int r16 = lane & 15;       // 0..15

  const f32x4 vzero = {0.f, 0.f, 0.f, 0.f};
  f32x4 acc[4][4];
#pragma unroll
  for (int a = 0; a < 4; ++a)
#pragma unroll
    for (int b = 0; b < 4; ++b) acc[a][b] = vzero;

  for (int k0 = 0; k0 < K; k0 += 32) {
    __syncthreads();               // protect LDS from overwrite
    gl_lds16(ga0 + k0, la0);
    gl_lds16(ga1 + k0, la1);
    gl_lds16(gb0 + k0, lb0);
    gl_lds16(gb1 + k0, lb1);
    __syncthreads();               // compiler drains vmcnt(0) before barrier

    bf16x8 av[4], bv[4];
#pragma unroll
    for (int mt = 0; mt < 4; ++mt)
      av[mt] = *(const bf16x8*)&sA[(wm + mt * 16 + r16) * 32 + quad * 8];
#pragma unroll
    for (int nt = 0; nt < 4; ++nt)
      bv[nt] = *(const bf16x8*)&sB[(wn + nt * 16 + r16) * 32 + quad * 8];
#pragma unroll
    for (int mt = 0; mt < 4; ++mt)
#pragma unroll
      for (int nt = 0; nt < 4; ++nt)
        acc[mt][nt] = __builtin_amdgcn_mfma_f32_16x16x32_bf16(av[mt], bv[nt], acc[mt][nt], 0, 0, 0);
  }

  // epilogue: C/D layout col=lane&15, row=quad*4+reg (m89-verified).
#pragma unroll
  for (int nt = 0; nt < 4; ++nt) {
    int col = j0 + wn + nt * 16 + r16;
    float bias = b2[col];
#pragma unroll
    for (int mt = 0; mt < 4; ++mt) {
      int rbase = i0 + wm + mt * 16 + quad * 4;
#pragma unroll
      for (int r = 0; r < 4; ++r) {
        size_t idx = (size_t)(rbase + r) * DIMD + col;
        out[idx] = ifeats[idx] + bias + acc[mt][nt][r];
      }
    }
  }
}

// ---------------------------------------------------------------------------
extern "C" void kernel_launch(void* const* d_in, const int* in_sizes, int n_in,
                              void* d_out, int out_size, void* d_ws, size_t ws_size,
                              hipStream_t stream) {
  const float* ifeats = (const float*)d_in[0];
  const float* tn     = (const float*)d_in[1];
  const float* ta     = (const float*)d_in[2];
  const float* cw     = (const float*)d_in[3];
  const float* cb     = (const float*)d_in[4];
  const float* w2     = (const float*)d_in[5];
  const float* b2     = (const float*)d_in[6];
  float* out = (float*)d_out;

  // ws layout: [0,8KB) shared conv rows | [8KB, 8KB+4MB) w2 bf16 | then x2 bf16 (32MB)
  float* shws = (float*)d_ws;
  u16* w2b = (u16*)((char*)d_ws + 8192);
  u16* x2  = (u16*)((char*)d_ws + 8192 + (size_t)DIMD * KDIM * 2);

  prep_shared<<<8, 256, 0, stream>>>(tn, ta, cw, cb, shws);
  cast_w2<<<(DIMD * KDIM / 8) / 256, 256, 0, stream>>>(w2, w2b);
  conv_gelu<<<(NROWS * KDIM / 8) / 256, 256, 0, stream>>>(ifeats, shws, cw, x2);
  gemm_bt<<<dim3(DIMD / 128, NROWS / 128), 256, 0, stream>>>(x2, w2b, ifeats, b2, out);
}

// Round 2
// 165.796 us; speedup vs baseline: 1.1726x; 1.1726x over previous
//
#include <hip/hip_runtime.h>
#include <cstdint>

#define DIMD 1024
#define NROWS 8192
#define KDIM 2048   // 2*DIM

typedef unsigned short u16;
typedef __bf16 bf16x8 __attribute__((ext_vector_type(8)));
typedef float f32x4 __attribute__((ext_vector_type(4)));

__device__ __forceinline__ u16 f2bf(float f) {
  unsigned u = __builtin_bit_cast(unsigned, f);
  return (u16)((u + 0x7FFFu + ((u >> 16) & 1u)) >> 16);  // RNE
}

// Exact-enough GELU: Abramowitz-Stegun 7.1.26 erf (|err| <= 1.5e-7), branch-free.
__device__ __forceinline__ float gelu_exact(float x) {
  float s = 0.70710678118654752f * x;
  float a = fabsf(s);
  float k = __fdividef(1.0f, fmaf(0.3275911f, a, 1.0f));
  float p = 1.061405429f;
  p = fmaf(p, k, -1.453152027f);
  p = fmaf(p, k, 1.421413741f);
  p = fmaf(p, k, -0.284496736f);
  p = fmaf(p, k, 0.254829592f);
  p = p * k;
  float e = __expf(-s * s);
  float erf_a = fmaf(-p, e, 1.0f);          // erf(|s|)
  float erf_s = copysignf(erf_a, s);
  return 0.5f * x * (1.0f + erf_s);
}

// ---------------------------------------------------------------------------
// Fused pre-kernel.
//  blocks [0, 8192): one ifeats row each -> conv(3x5,pad 2) + bias + exact gelu
//                    -> x2 row [2048] bf16. Row + tfeat rows staged in LDS.
//  blocks [8192, 9216): cast w2 fp32 -> bf16, 8 elems/thread.
// ---------------------------------------------------------------------------
__global__ __launch_bounds__(256) void pre_kernel(
    const float* __restrict__ ifeats, const float* __restrict__ tn,
    const float* __restrict__ ta, const float* __restrict__ cw,
    const float* __restrict__ cb, const float* __restrict__ w2,
    u16* __restrict__ x2, u16* __restrict__ w2b) {
  const int b = blockIdx.x;
  const int t = threadIdx.x;
  if (b < NROWS) {
    __shared__ float si[DIMD], sn[DIMD], sa[DIMD];
    ((float4*)si)[t] = ((const float4*)(ifeats + (size_t)b * DIMD))[t];
    ((float4*)sn)[t] = ((const float4*)tn)[t];
    ((float4*)sa)[t] = ((const float4*)ta)[t];
    __syncthreads();
    const int c = t >> 7;              // channel 0/1
    const int w0 = (t & 127) << 3;     // 0..1016
    float cwn[5], cwa[5], cwi[5];
#pragma unroll
    for (int k = 0; k < 5; ++k) {
      cwn[k] = cw[c * 15 + k];
      cwa[k] = cw[c * 15 + 5 + k];
      cwi[k] = cw[c * 15 + 10 + k];
    }
    const float bias = cb[c];
    float wn[12], wa[12], wi[12];
#pragma unroll
    for (int j = 0; j < 12; ++j) {
      int wp = w0 - 2 + j;
      bool ok = (wp >= 0) && (wp < DIMD);
      wn[j] = ok ? sn[wp] : 0.f;
      wa[j] = ok ? sa[wp] : 0.f;
      wi[j] = ok ? si[wp] : 0.f;
    }
    union { u16 o[8]; uint4 u; } pk;
#pragma unroll
    for (int s = 0; s < 8; ++s) {
      float x = bias;
#pragma unroll
      for (int k = 0; k < 5; ++k) {
        x = fmaf(cwn[k], wn[s + k], x);
        x = fmaf(cwa[k], wa[s + k], x);
        x = fmaf(cwi[k], wi[s + k], x);
      }
      pk.o[s] = f2bf(gelu_exact(x));
    }
    *(uint4*)(x2 + (size_t)b * KDIM + c * DIMD + w0) = pk.u;
  } else {
    // cast w2: 1024 blocks x 256 threads x 8 elems = 2,097,152
    const int t2 = (b - NROWS) * 256 + t;
    const float4* p = (const float4*)(w2 + (size_t)t2 * 8);
    float4 a = p[0], bb = p[1];
    union { u16 o[8]; uint4 v; } pk;
    pk.o[0] = f2bf(a.x);  pk.o[1] = f2bf(a.y);  pk.o[2] = f2bf(a.z);  pk.o[3] = f2bf(a.w);
    pk.o[4] = f2bf(bb.x); pk.o[5] = f2bf(bb.y); pk.o[6] = f2bf(bb.z); pk.o[7] = f2bf(bb.w);
    *(uint4*)(w2b + (size_t)t2 * 8) = pk.v;
  }
}

// ---------------------------------------------------------------------------
// GEMM: out[i][j] = ifeats[i][j] + b2[j] + sum_k x2[i][k] * w2b[j][k]
// 128x128 tile, BK=64, double-buffered LDS with true async prefetch:
// one barrier per stage; next stage's global_load_lds issued right after the
// barrier so its vmcnt drain at the NEXT barrier hits aged loads.
// XOR chunk swizzle (chunk ^ (row&7)) keeps ds_read_b128 at minimum conflicts.
// ---------------------------------------------------------------------------
__device__ __forceinline__ void gl_lds16(const u16* g, u16* l) {
  __builtin_amdgcn_global_load_lds(
      (__attribute__((address_space(1))) void*)g,
      (__attribute__((address_space(3))) void*)l, 16, 0, 0);
}

#define BK 64  // u16 per row per stage

__global__ __launch_bounds__(256, 2) void gemm_bt(
    const u16* __restrict__ A,      // x2 bf16 [8192, 2048]
    const u16* __restrict__ B,      // w2 bf16 [1024, 2048]
    const float* __restrict__ ifeats,
    const float* __restrict__ b2,
    float* __restrict__ out) {
  constexpr int K = KDIM;
  __shared__ __align__(16) u16 sA[2][128 * BK];  // 16 KB per buf
  __shared__ __align__(16) u16 sB[2][128 * BK];

  const int tid = threadIdx.x;
  const int wv = tid >> 6;
  const int lane = tid & 63;
  const int i0 = blockIdx.y * 128;
  const int j0 = blockIdx.x * 128;
  const int wm = (wv & 1) * 64;
  const int wn = (wv >> 1) * 64;
  const int quad = lane >> 4;
  const int r16 = lane & 15;
  const int sw = r16 & 7;

  // staging: per wave 4 issues for A + 4 for B; issue i covers 8 rows
  // (wv*32 + i*8 + lane/8), 16B chunk (lane&7) XOR-swizzled by row%8.
  const int srow = lane >> 3;                 // 0..7
  const int schunk = (lane & 7) ^ srow;       // global 16B chunk index
  const u16* gA[4];
  const u16* gB[4];
#pragma unroll
  for (int i = 0; i < 4; ++i) {
    int r = wv * 32 + i * 8 + srow;
    gA[i] = A + (size_t)(i0 + r) * K + schunk * 8;
    gB[i] = B + (size_t)(j0 + r) * K + schunk * 8;
  }

  const f32x4 vzero = {0.f, 0.f, 0.f, 0.f};
  f32x4 acc[4][4];
#pragma unroll
  for (int a = 0; a < 4; ++a)
#pragma unroll
    for (int b = 0; b < 4; ++b) acc[a][b] = vzero;

  // stage loader: 8 global_load_lds (16B) per wave into buf
  auto stage = [&](int buf, int k0) {
#pragma unroll
    for (int i = 0; i < 4; ++i) {
      u16* la = &sA[buf][(wv * 32 + i * 8) * BK];
      u16* lb = &sB[buf][(wv * 32 + i * 8) * BK];
      gl_lds16(gA[i] + k0, la);
      gl_lds16(gB[i] + k0, lb);
    }
  };

  auto compute = [&](int buf) {
#pragma unroll
    for (int s = 0; s < 2; ++s) {
      bf16x8 av[4], bv[4];
#pragma unroll
      for (int mt = 0; mt < 4; ++mt)
        av[mt] = *(const bf16x8*)&sA[buf][(wm + mt * 16 + r16) * BK + (((s * 4 + quad) ^ sw) << 3)];
#pragma unroll
      for (int nt = 0; nt < 4; ++nt)
        bv[nt] = *(const bf16x8*)&sB[buf][(wn + nt * 16 + r16) * BK + (((s * 4 + quad) ^ sw) << 3)];
#pragma unroll
      for (int mt = 0; mt < 4; ++mt)
#pragma unroll
        for (int nt = 0; nt < 4; ++nt)
          acc[mt][nt] = __builtin_amdgcn_mfma_f32_16x16x32_bf16(av[mt], bv[nt], acc[mt][nt], 0, 0, 0);
    }
  };

  stage(0, 0);
  for (int k0 = 0; k0 < K; k0 += 2 * BK) {
    __syncthreads();                    // drains buf0 loads; buf1 free
    if (k0 + BK < K) stage(1, k0 + BK); // prefetch next stage (async)
    compute(0);
    __syncthreads();                    // drains buf1 loads (aged 1 phase)
    if (k0 + 2 * BK < K) stage(0, k0 + 2 * BK);
    compute(1);
  }

  // epilogue: C/D layout col=lane&15, row=quad*4+reg
#pragma unroll
  for (int nt = 0; nt < 4; ++nt) {
    int col = j0 + wn + nt * 16 + r16;
    float bias = b2[col];
#pragma unroll
    for (int mt = 0; mt < 4; ++mt) {
      int rbase = i0 + wm + mt * 16 + quad * 4;
#pragma unroll
      for (int r = 0; r < 4; ++r) {
        size_t idx = (size_t)(rbase + r) * DIMD + col;
        out[idx] = ifeats[idx] + bias + acc[mt][nt][r];
      }
    }
  }
}

// ---------------------------------------------------------------------------
extern "C" void kernel_launch(void* const* d_in, const int* in_sizes, int n_in,
                              void* d_out, int out_size, void* d_ws, size_t ws_size,
                              hipStream_t stream) {
  const float* ifeats = (const float*)d_in[0];
  const float* tn     = (const float*)d_in[1];
  const float* ta     = (const float*)d_in[2];
  const float* cw     = (const float*)d_in[3];
  const float* cb     = (const float*)d_in[4];
  const float* w2     = (const float*)d_in[5];
  const float* b2     = (const float*)d_in[6];
  float* out = (float*)d_out;

  // ws: [0, 4MB) w2 bf16 | [4MB, 36MB) x2 bf16
  u16* w2b = (u16*)d_ws;
  u16* x2  = (u16*)((char*)d_ws + (size_t)DIMD * KDIM * 2);

  pre_kernel<<<NROWS + (DIMD * KDIM / 8) / 256, 256, 0, stream>>>(
      ifeats, tn, ta, cw, cb, w2, x2, w2b);
  gemm_bt<<<dim3(DIMD / 128, NROWS / 128), 256, 0, stream>>>(x2, w2b, ifeats, b2, out);
}

// Round 3
// 161.413 us; speedup vs baseline: 1.2044x; 1.0272x over previous
//
#include <hip/hip_runtime.h>
#include <cstdint>

#define DIMD 1024
#define NROWS 8192
#define KDIM 2048   // 2*DIM

typedef unsigned short u16;
typedef __bf16 bf16x8 __attribute__((ext_vector_type(8)));
typedef float f32x4 __attribute__((ext_vector_type(4)));

__device__ __forceinline__ u16 f2bf(float f) {
  unsigned u = __builtin_bit_cast(unsigned, f);
  return (u16)((u + 0x7FFFu + ((u >> 16) & 1u)) >> 16);  // RNE
}

// Branch-free exact-enough GELU (A&S 7.1.26 erf, |err| <= 1.5e-7).
__device__ __forceinline__ float gelu_exact(float x) {
  float s = 0.70710678118654752f * x;
  float a = fabsf(s);
  float k = __fdividef(1.0f, fmaf(0.3275911f, a, 1.0f));
  float p = 1.061405429f;
  p = fmaf(p, k, -1.453152027f);
  p = fmaf(p, k, 1.421413741f);
  p = fmaf(p, k, -0.284496736f);
  p = fmaf(p, k, 0.254829592f);
  p = p * k;
  float e = __expf(-s * s);
  float erf_s = copysignf(fmaf(-p, e, 1.0f), s);
  return 0.5f * x * (1.0f + erf_s);
}

// ---------------------------------------------------------------------------
// Fused pre-kernel: conv(3x5)+bias+gelu -> x2 bf16, and w2 fp32->bf16 cast.
// ---------------------------------------------------------------------------
__global__ __launch_bounds__(256) void pre_kernel(
    const float* __restrict__ ifeats, const float* __restrict__ tn,
    const float* __restrict__ ta, const float* __restrict__ cw,
    const float* __restrict__ cb, const float* __restrict__ w2,
    u16* __restrict__ x2, u16* __restrict__ w2b) {
  const int b = blockIdx.x;
  const int t = threadIdx.x;
  if (b < NROWS) {
    __shared__ float si[DIMD], sn[DIMD], sa[DIMD];
    ((float4*)si)[t] = ((const float4*)(ifeats + (size_t)b * DIMD))[t];
    ((float4*)sn)[t] = ((const float4*)tn)[t];
    ((float4*)sa)[t] = ((const float4*)ta)[t];
    __syncthreads();
    const int c = t >> 7;
    const int w0 = (t & 127) << 3;
    float cwn[5], cwa[5], cwi[5];
#pragma unroll
    for (int k = 0; k < 5; ++k) {
      cwn[k] = cw[c * 15 + k];
      cwa[k] = cw[c * 15 + 5 + k];
      cwi[k] = cw[c * 15 + 10 + k];
    }
    const float bias = cb[c];
    float wn[12], wa[12], wi[12];
#pragma unroll
    for (int j = 0; j < 12; ++j) {
      int wp = w0 - 2 + j;
      bool ok = (wp >= 0) && (wp < DIMD);
      wn[j] = ok ? sn[wp] : 0.f;
      wa[j] = ok ? sa[wp] : 0.f;
      wi[j] = ok ? si[wp] : 0.f;
    }
    union { u16 o[8]; uint4 u; } pk;
#pragma unroll
    for (int s = 0; s < 8; ++s) {
      float x = bias;
#pragma unroll
      for (int k = 0; k < 5; ++k) {
        x = fmaf(cwn[k], wn[s + k], x);
        x = fmaf(cwa[k], wa[s + k], x);
        x = fmaf(cwi[k], wi[s + k], x);
      }
      pk.o[s] = f2bf(gelu_exact(x));
    }
    *(uint4*)(x2 + (size_t)b * KDIM + c * DIMD + w0) = pk.u;
  } else {
    const int t2 = (b - NROWS) * 256 + t;
    const float4* p = (const float4*)(w2 + (size_t)t2 * 8);
    float4 a = p[0], bb = p[1];
    union { u16 o[8]; uint4 v; } pk;
    pk.o[0] = f2bf(a.x);  pk.o[1] = f2bf(a.y);  pk.o[2] = f2bf(a.z);  pk.o[3] = f2bf(a.w);
    pk.o[4] = f2bf(bb.x); pk.o[5] = f2bf(bb.y); pk.o[6] = f2bf(bb.z); pk.o[7] = f2bf(bb.w);
    *(uint4*)(w2b + (size_t)t2 * 8) = pk.v;
  }
}

// ---------------------------------------------------------------------------
// GEMM: out[i][j] = ifeats[i][j] + b2[j] + sum_k x2[i][k] * w2b[j][k]
// 128x128 tile, 8 waves (512 thr) -> 16 waves/CU at 2 blocks/CU (occupancy
// was the round-2 bottleneck). BK=64 double-buffered, async prefetch issued
// right after each barrier. XOR chunk swizzle -> 0 bank conflicts (verified).
// XCD swizzle: xcd=id&7 owns M-strip [xcd*8, xcd*8+8) x all 8 N-blocks.
// ---------------------------------------------------------------------------
__device__ __forceinline__ void gl_lds16(const u16* g, u16* l) {
  __builtin_amdgcn_global_load_lds(
      (__attribute__((address_space(1))) void*)g,
      (__attribute__((address_space(3))) void*)l, 16, 0, 0);
}

#define BK 64  // u16 per row per stage

__global__ __launch_bounds__(512, 4) void gemm_bt(
    const u16* __restrict__ A,      // x2 bf16 [8192, 2048]
    const u16* __restrict__ B,      // w2 bf16 [1024, 2048]
    const float* __restrict__ ifeats,
    const float* __restrict__ b2,
    float* __restrict__ out) {
  constexpr int K = KDIM;
  __shared__ __align__(16) u16 sA[2][128 * BK];  // 16 KB per buf
  __shared__ __align__(16) u16 sB[2][128 * BK];

  const int tid = threadIdx.x;
  const int wv = tid >> 6;         // wave 0..7
  const int lane = tid & 63;
  // XCD-aware swizzle: linear id -> (i_blk, j_blk)
  const int id = blockIdx.x;       // 0..511
  const int xcd = id & 7;
  const int s_ = id >> 3;          // 0..63
  const int i0 = (xcd * 8 + (s_ >> 3)) * 128;
  const int j0 = (s_ & 7) * 128;

  const int wm = (wv & 1) * 64;    // wave tile: 64 (M) x 32 (N)
  const int wn = (wv >> 1) * 32;
  const int quad = lane >> 4;
  const int r16 = lane & 15;
  const int sw = r16 & 7;

  // staging: per wave 16 rows of A + 16 of B per stage; 8 rows per issue.
  const int srow = lane >> 3;                 // 0..7
  const int schunk = (lane & 7) ^ srow;       // XOR-swizzled 16B chunk
  const u16* gA[2];
  const u16* gB[2];
#pragma unroll
  for (int i = 0; i < 2; ++i) {
    int r = wv * 16 + i * 8 + srow;
    gA[i] = A + (size_t)(i0 + r) * K + schunk * 8;
    gB[i] = B + (size_t)(j0 + r) * K + schunk * 8;
  }

  const f32x4 vzero = {0.f, 0.f, 0.f, 0.f};
  f32x4 acc[4][2];
#pragma unroll
  for (int a = 0; a < 4; ++a)
#pragma unroll
    for (int b = 0; b < 2; ++b) acc[a][b] = vzero;

  auto stage = [&](int buf, int k0) {
#pragma unroll
    for (int i = 0; i < 2; ++i) {
      u16* la = &sA[buf][(wv * 16 + i * 8) * BK];
      u16* lb = &sB[buf][(wv * 16 + i * 8) * BK];
      gl_lds16(gA[i] + k0, la);
      gl_lds16(gB[i] + k0, lb);
    }
  };

  auto compute = [&](int buf) {
#pragma unroll
    for (int s = 0; s < 2; ++s) {
      bf16x8 av[4], bv[2];
#pragma unroll
      for (int mt = 0; mt < 4; ++mt)
        av[mt] = *(const bf16x8*)&sA[buf][(wm + mt * 16 + r16) * BK + (((s * 4 + quad) ^ sw) << 3)];
#pragma unroll
      for (int nt = 0; nt < 2; ++nt)
        bv[nt] = *(const bf16x8*)&sB[buf][(wn + nt * 16 + r16) * BK + (((s * 4 + quad) ^ sw) << 3)];
#pragma unroll
      for (int mt = 0; mt < 4; ++mt)
#pragma unroll
        for (int nt = 0; nt < 2; ++nt)
          acc[mt][nt] = __builtin_amdgcn_mfma_f32_16x16x32_bf16(av[mt], bv[nt], acc[mt][nt], 0, 0, 0);
    }
  };

  stage(0, 0);
  for (int k0 = 0; k0 < K; k0 += 2 * BK) {
    __syncthreads();                    // drains buf0 loads; buf1 free
    if (k0 + BK < K) stage(1, k0 + BK); // async prefetch next stage
    compute(0);
    __syncthreads();                    // drains buf1 loads (aged one phase)
    if (k0 + 2 * BK < K) stage(0, k0 + 2 * BK);
    compute(1);
  }

  // epilogue: C/D layout col=lane&15, row=quad*4+reg
#pragma unroll
  for (int nt = 0; nt < 2; ++nt) {
    int col = j0 + wn + nt * 16 + r16;
    float bias = b2[col];
#pragma unroll
    for (int mt = 0; mt < 4; ++mt) {
      int rbase = i0 + wm + mt * 16 + quad * 4;
#pragma unroll
      for (int r = 0; r < 4; ++r) {
        size_t idx = (size_t)(rbase + r) * DIMD + col;
        out[idx] = ifeats[idx] + bias + acc[mt][nt][r];
      }
    }
  }
}

// ---------------------------------------------------------------------------
extern "C" void kernel_launch(void* const* d_in, const int* in_sizes, int n_in,
                              void* d_out, int out_size, void* d_ws, size_t ws_size,
                              hipStream_t stream) {
  const float* ifeats = (const float*)d_in[0];
  const float* tn     = (const float*)d_in[1];
  const float* ta     = (const float*)d_in[2];
  const float* cw     = (const float*)d_in[3];
  const float* cb     = (const float*)d_in[4];
  const float* w2     = (const float*)d_in[5];
  const float* b2     = (const float*)d_in[6];
  float* out = (float*)d_out;

  // ws: [0, 4MB) w2 bf16 | [4MB, 36MB) x2 bf16
  u16* w2b = (u16*)d_ws;
  u16* x2  = (u16*)((char*)d_ws + (size_t)DIMD * KDIM * 2);

  pre_kernel<<<NROWS + (DIMD * KDIM / 8) / 256, 256, 0, stream>>>(
      ifeats, tn, ta, cw, cb, w2, x2, w2b);
  gemm_bt<<<512, 512, 0, stream>>>(x2, w2b, ifeats, b2, out);
}